// Round 1
// baseline (1067.382 us; speedup 1.0000x reference)
//
#include <hip/hip_runtime.h>
#include <hip/hip_bf16.h>
#include <math.h>

// Problem constants
#define BB 512
#define LL 10000
#define HH 2
#define NN 32
#define NL 4
#define TT 64
#define CHK 157           // ceil(10000/64)
#define BL (BB*LL)        // 5,120,000

// Workspace layout (in floats)
#define OFF_U0   0
#define OFF_U1   10240000          // B*H*L
#define OFF_ST   20480000          // B*CHK*128 = 10,289,152
#define OFF_TAB  30769152
// tables: lam[NL*H*N*2]=512, lamT 512, Cn 512, Kt[NL*H*T]=512, P[NL*H*N*T*2]=32768

// ---------------------------------------------------------------- setup
__global__ void setup_kernel(const float* __restrict__ log_dt,
                             const float* __restrict__ log_A_real,
                             const float* __restrict__ A_imag,
                             const float* __restrict__ Cin,
                             float* __restrict__ lam, float* __restrict__ lamT,
                             float* __restrict__ Cn, float* __restrict__ Kt,
                             float* __restrict__ P) {
    int ih = blockIdx.x;          // 0..7 = layer*H + h
    int tid = threadIdx.x;        // 0..63
    __shared__ float s_dtA[NN * 2];
    __shared__ float s_Cn[NN * 2];
    float dt = expf(log_dt[ih]);
    if (tid < NN) {
        int n = tid;
        float aRe = -expf(log_A_real[ih * NN + n]);
        float aIm = A_imag[ih * NN + n];
        float dRe = aRe * dt, dIm = aIm * dt;
        s_dtA[2 * n] = dRe; s_dtA[2 * n + 1] = dIm;
        float e = expf(dRe);
        float sn, cs; sincosf(dIm, &sn, &cs);
        float lRe = e * cs, lIm = e * sn;
        lam[ih * NN * 2 + 2 * n] = lRe;
        lam[ih * NN * 2 + 2 * n + 1] = lIm;
        float eT = expf((float)TT * dRe);
        float snT, csT; sincosf((float)TT * dIm, &snT, &csT);
        lamT[ih * NN * 2 + 2 * n] = eT * csT;
        lamT[ih * NN * 2 + 2 * n + 1] = eT * snT;
        // Cn = (C0 + i C1) * (lam - 1) / A
        float C0 = Cin[(ih * NN + n) * 2];
        float C1 = Cin[(ih * NN + n) * 2 + 1];
        float numRe = lRe - 1.0f, numIm = lIm;
        float den = aRe * aRe + aIm * aIm;
        float qRe = (numRe * aRe + numIm * aIm) / den;
        float qIm = (numIm * aRe - numRe * aIm) / den;
        float cnRe = C0 * qRe - C1 * qIm;
        float cnIm = C0 * qIm + C1 * qRe;
        Cn[ih * NN * 2 + 2 * n] = cnRe;
        Cn[ih * NN * 2 + 2 * n + 1] = cnIm;
        s_Cn[2 * n] = cnRe; s_Cn[2 * n + 1] = cnIm;
        // P[n][l] = lam^{l+1}
        for (int l = 0; l < TT; l++) {
            float p = (float)(l + 1);
            float ee = expf(p * dRe);
            float ss, cc; sincosf(p * dIm, &ss, &cc);
            P[(ih * NN + n) * TT * 2 + 2 * l]     = ee * cc;
            P[(ih * NN + n) * TT * 2 + 2 * l + 1] = ee * ss;
        }
    }
    __syncthreads();
    // Kt[d] = 2 * sum_n Re(Cn * lam^d), d = tid (0..63)
    int d = tid;
    float acc = 0.0f;
    for (int n = 0; n < NN; n++) {
        float dRe = s_dtA[2 * n], dIm = s_dtA[2 * n + 1];
        float ee = expf((float)d * dRe);
        float ss, cc; sincosf((float)d * dIm, &ss, &cc);
        acc += s_Cn[2 * n] * (ee * cc) - s_Cn[2 * n + 1] * (ee * ss);
    }
    Kt[ih * TT + d] = 2.0f * acc;
}

// ---------------------------------------------------------------- embed: u0 = x@W1^T + b1
__global__ __launch_bounds__(256) void embed_kernel(const float* __restrict__ x,
                             const float* __restrict__ W1, const float* __restrict__ b1,
                             float* __restrict__ u) {
    int idx = blockIdx.x * blockDim.x + threadIdx.x;
    if (idx >= BL) return;
    int b = idx / LL, l = idx - b * LL;
    float x0 = x[idx * 3], x1 = x[idx * 3 + 1], x2 = x[idx * 3 + 2];
    float u0 = fmaf(W1[0], x0, fmaf(W1[1], x1, fmaf(W1[2], x2, b1[0])));
    float u1 = fmaf(W1[3], x0, fmaf(W1[4], x1, fmaf(W1[5], x2, b1[1])));
    u[(b * HH + 0) * LL + l] = u0;
    u[(b * HH + 1) * LL + l] = u1;
}

// ---------------------------------------------------------------- phase A: chunk-local final states
__global__ __launch_bounds__(256) void phaseA_kernel(const float* __restrict__ u,
                              const float* __restrict__ lam,
                              float* __restrict__ st, int layer) {
    int gwave = (blockIdx.x * blockDim.x + threadIdx.x) >> 6;   // exactly B*CHK waves
    int lane = threadIdx.x & 63;
    int b = gwave / CHK, c = gwave - b * CHK;
    int h = lane >> 5, n = lane & 31;
    float lRe = lam[(layer * HH + h) * NN * 2 + 2 * n];
    float lIm = lam[(layer * HH + h) * NN * 2 + 2 * n + 1];
    const float* up = u + (b * HH + h) * LL + c * TT;
    int rem = LL - c * TT;
    int j0 = lane & 31;
    float uA = (j0 < rem) ? up[j0] : 0.0f;
    float uB = (32 + j0 < rem) ? up[32 + j0] : 0.0f;
    float sRe = 0.0f, sIm = 0.0f;
#pragma unroll
    for (int j = 0; j < TT; j++) {
        float src = (j < 32) ? uA : uB;
        float uv = __shfl(src, (lane & 32) | (j & 31), 64);
        float nRe = fmaf(lRe, sRe, fmaf(-lIm, sIm, uv));
        float nIm = fmaf(lRe, sIm, lIm * sRe);
        sRe = nRe; sIm = nIm;
    }
    st[(b * CHK + c) * 128 + lane] = sRe;
    st[(b * CHK + c) * 128 + 64 + lane] = sIm;
}

// ---------------------------------------------------------------- phase B: cross-chunk prefix scan (in place)
__global__ __launch_bounds__(256) void phaseB_kernel(const float* __restrict__ lamT,
                              float* __restrict__ st, int layer) {
    int t = blockIdx.x * blockDim.x + threadIdx.x;   // exactly B*64 threads
    int b = t >> 6, lane = t & 63;
    int h = lane >> 5, n = lane & 31;
    float lRe = lamT[(layer * HH + h) * NN * 2 + 2 * n];
    float lIm = lamT[(layer * HH + h) * NN * 2 + 2 * n + 1];
    float* base = st + (size_t)b * CHK * 128;
    float rRe = 0.0f, rIm = 0.0f;
    float nxRe = base[lane], nxIm = base[64 + lane];
    for (int c = 0; c < CHK; c++) {
        float sfRe = nxRe, sfIm = nxIm;
        if (c + 1 < CHK) {
            nxRe = base[(c + 1) * 128 + lane];
            nxIm = base[(c + 1) * 128 + 64 + lane];
        }
        base[c * 128 + lane] = rRe;
        base[c * 128 + 64 + lane] = rIm;
        float tRe = fmaf(lRe, rRe, fmaf(-lIm, rIm, sfRe));
        float tIm = fmaf(lRe, rIm, fmaf(lIm, rRe, sfIm));
        rRe = tRe; rIm = tIm;
    }
}

// ---------------------------------------------------------------- phase C: time-parallel y + pointwise + GLU
__global__ __launch_bounds__(256) void phaseC_kernel(const float* __restrict__ u,
                              float* __restrict__ uNext,
                              const float* __restrict__ Cn, const float* __restrict__ Kt,
                              const float* __restrict__ P, const float* __restrict__ st,
                              const float* __restrict__ Dp, const float* __restrict__ Wout,
                              const float* __restrict__ bout, int layer) {
    int wSlot = threadIdx.x >> 6;
    int lane = threadIdx.x & 63;
    int gwave = blockIdx.x * 4 + wSlot;      // grid sized exactly: B*CHK/4
    __shared__ float s_u[4][2][TT];
    __shared__ float s_w[4][64][2];
    __shared__ float s_k[4][2][TT];
    int b = gwave / CHK, c = gwave - b * CHK;
    int h = lane >> 5, n = lane & 31;
    int l0 = c * TT;
    int rem = LL - l0;
    const float* ub = u + (size_t)b * HH * LL + l0;
    s_u[wSlot][0][lane] = (lane < rem) ? ub[lane] : 0.0f;
    s_u[wSlot][1][lane] = (lane < rem) ? ub[LL + lane] : 0.0f;
    float s0Re = st[(b * CHK + c) * 128 + lane];
    float s0Im = st[(b * CHK + c) * 128 + 64 + lane];
    float cnRe = Cn[(layer * HH + h) * NN * 2 + 2 * n];
    float cnIm = Cn[(layer * HH + h) * NN * 2 + 2 * n + 1];
    s_w[wSlot][lane][0] = cnRe * s0Re - cnIm * s0Im;
    s_w[wSlot][lane][1] = cnRe * s0Im + cnIm * s0Re;
    s_k[wSlot][0][lane] = Kt[(layer * HH + 0) * TT + lane];
    s_k[wSlot][1][lane] = Kt[(layer * HH + 1) * TT + lane];
    __syncthreads();
    int l = lane;  // timestep within chunk
    // correction: 2*Re( sum_n w_n * lam_n^{l+1} )
    const float* P0 = P + (size_t)(layer * HH + 0) * NN * TT * 2;
    const float* P1 = P + (size_t)(layer * HH + 1) * NN * TT * 2;
    float acc0 = 0.0f, acc1 = 0.0f;
#pragma unroll 8
    for (int nn = 0; nn < NN; nn++) {
        float2 p0 = *(const float2*)(P0 + nn * TT * 2 + 2 * l);
        acc0 = fmaf(s_w[wSlot][nn][0], p0.x, fmaf(-s_w[wSlot][nn][1], p0.y, acc0));
        float2 p1 = *(const float2*)(P1 + nn * TT * 2 + 2 * l);
        acc1 = fmaf(s_w[wSlot][32 + nn][0], p1.x, fmaf(-s_w[wSlot][32 + nn][1], p1.y, acc1));
    }
    float y0 = 2.0f * acc0, y1 = 2.0f * acc1;
    // local causal conv within chunk
    float cv0 = 0.0f, cv1 = 0.0f;
#pragma unroll 8
    for (int d = 0; d < TT; d++) {
        int idx = (l - d) & 63;
        float uv0 = s_u[wSlot][0][idx];
        float uv1 = s_u[wSlot][1][idx];
        bool ok = (d <= l);
        uv0 = ok ? uv0 : 0.0f;
        uv1 = ok ? uv1 : 0.0f;
        cv0 = fmaf(s_k[wSlot][0][d], uv0, cv0);
        cv1 = fmaf(s_k[wSlot][1][d], uv1, cv1);
    }
    y0 += cv0; y1 += cv1;
    // D skip
    float u0v = s_u[wSlot][0][l], u1v = s_u[wSlot][1][l];
    y0 = fmaf(Dp[layer * HH + 0], u0v, y0);
    y1 = fmaf(Dp[layer * HH + 1], u1v, y1);
    // exact GELU
    y0 = 0.5f * y0 * (1.0f + erff(y0 * 0.70710678118654752f));
    y1 = 0.5f * y1 * (1.0f + erff(y1 * 0.70710678118654752f));
    // channel mix (Conv1d H->2H, kernel 1) + GLU
    const float* Wo = Wout + layer * 8;
    const float* bo = bout + layer * 4;
    float z0 = fmaf(Wo[0], y0, fmaf(Wo[1], y1, bo[0]));
    float z1 = fmaf(Wo[2], y0, fmaf(Wo[3], y1, bo[1]));
    float z2 = fmaf(Wo[4], y0, fmaf(Wo[5], y1, bo[2]));
    float z3 = fmaf(Wo[6], y0, fmaf(Wo[7], y1, bo[3]));
    float g2 = 1.0f / (1.0f + expf(-z2));
    float g3 = 1.0f / (1.0f + expf(-z3));
    if (l < rem) {
        uNext[(size_t)b * HH * LL + l0 + l] = z0 * g2;
        uNext[(size_t)b * HH * LL + LL + l0 + l] = z1 * g3;
    }
}

// ---------------------------------------------------------------- final: out = u^T @ W2^T + b2
__global__ __launch_bounds__(256) void final_kernel(const float* __restrict__ u,
                             const float* __restrict__ W2, const float* __restrict__ b2,
                             float* __restrict__ out) {
    int idx = blockIdx.x * blockDim.x + threadIdx.x;
    if (idx >= BL) return;
    int b = idx / LL, l = idx - b * LL;
    float u0 = u[(size_t)b * HH * LL + l];
    float u1 = u[(size_t)b * HH * LL + LL + l];
    float o0 = fmaf(u0, W2[0], fmaf(u1, W2[1], b2[0]));
    float o1 = fmaf(u0, W2[2], fmaf(u1, W2[3], b2[1]));
    ((float2*)out)[idx] = make_float2(o0, o1);
}

extern "C" void kernel_launch(void* const* d_in, const int* in_sizes, int n_in,
                              void* d_out, int out_size, void* d_ws, size_t ws_size,
                              hipStream_t stream) {
    const float* x         = (const float*)d_in[0];
    const float* W1        = (const float*)d_in[1];
    const float* b1        = (const float*)d_in[2];
    const float* W2        = (const float*)d_in[3];
    const float* b2        = (const float*)d_in[4];
    const float* log_dt    = (const float*)d_in[5];
    const float* log_A_real= (const float*)d_in[6];
    const float* A_imag    = (const float*)d_in[7];
    const float* Cin       = (const float*)d_in[8];
    const float* Dp        = (const float*)d_in[9];
    const float* Wout      = (const float*)d_in[10];
    const float* bout      = (const float*)d_in[11];
    float* out = (float*)d_out;
    float* ws = (float*)d_ws;

    float* U0   = ws + OFF_U0;
    float* U1   = ws + OFF_U1;
    float* ST   = ws + OFF_ST;
    float* lam  = ws + OFF_TAB;
    float* lamT = lam + 512;
    float* Cn   = lamT + 512;
    float* Kt   = Cn + 512;
    float* P    = Kt + 512;

    setup_kernel<<<dim3(NL * HH), dim3(64), 0, stream>>>(log_dt, log_A_real, A_imag, Cin,
                                                         lam, lamT, Cn, Kt, P);
    embed_kernel<<<dim3(BL / 256), dim3(256), 0, stream>>>(x, W1, b1, U0);

    float* cur = U0;
    float* nxt = U1;
    for (int i = 0; i < NL; i++) {
        phaseA_kernel<<<dim3(BB * CHK / 4), dim3(256), 0, stream>>>(cur, lam, ST, i);
        phaseB_kernel<<<dim3(BB * 64 / 256), dim3(256), 0, stream>>>(lamT, ST, i);
        phaseC_kernel<<<dim3(BB * CHK / 4), dim3(256), 0, stream>>>(cur, nxt, Cn, Kt, P, ST,
                                                                    Dp, Wout, bout, i);
        float* tmp = cur; cur = nxt; nxt = tmp;
    }
    final_kernel<<<dim3(BL / 256), dim3(256), 0, stream>>>(cur, W2, b2, out);
}

// Round 2
// 967.772 us; speedup vs baseline: 1.1029x; 1.1029x over previous
//
#include <hip/hip_runtime.h>
#include <hip/hip_bf16.h>
#include <math.h>

// Problem constants
#define BB 512
#define LL 10000
#define HH 2
#define NN 32
#define NL 4
#define TT 64
#define CHK 157           // ceil(10000/64)
#define QG 40             // chunk groups of 4 per sequence: 40*4 >= 157
#define BL (BB*LL)        // 5,120,000

// Workspace layout (in floats)
#define OFF_U0   0
#define OFF_U1   10240000          // B*H*L
#define OFF_ST   20480000          // B*CHK*128 = 10,289,152
#define OFF_TAB  30769152
// tables: lam[NL*H*N*2]=512, lamT 512, Cn 512, Kt[NL*H*T]=512, P[NL*H*N*T*2]=32768

// ---------------------------------------------------------------- setup
__global__ void setup_kernel(const float* __restrict__ log_dt,
                             const float* __restrict__ log_A_real,
                             const float* __restrict__ A_imag,
                             const float* __restrict__ Cin,
                             float* __restrict__ lam, float* __restrict__ lamT,
                             float* __restrict__ Cn, float* __restrict__ Kt,
                             float* __restrict__ P) {
    int ih = blockIdx.x;          // 0..7 = layer*H + h
    int tid = threadIdx.x;        // 0..63
    __shared__ float s_dtA[NN * 2];
    __shared__ float s_Cn[NN * 2];
    float dt = expf(log_dt[ih]);
    if (tid < NN) {
        int n = tid;
        float aRe = -expf(log_A_real[ih * NN + n]);
        float aIm = A_imag[ih * NN + n];
        float dRe = aRe * dt, dIm = aIm * dt;
        s_dtA[2 * n] = dRe; s_dtA[2 * n + 1] = dIm;
        float e = expf(dRe);
        float sn, cs; sincosf(dIm, &sn, &cs);
        float lRe = e * cs, lIm = e * sn;
        lam[ih * NN * 2 + 2 * n] = lRe;
        lam[ih * NN * 2 + 2 * n + 1] = lIm;
        float eT = expf((float)TT * dRe);
        float snT, csT; sincosf((float)TT * dIm, &snT, &csT);
        lamT[ih * NN * 2 + 2 * n] = eT * csT;
        lamT[ih * NN * 2 + 2 * n + 1] = eT * snT;
        // Cn = (C0 + i C1) * (lam - 1) / A
        float C0 = Cin[(ih * NN + n) * 2];
        float C1 = Cin[(ih * NN + n) * 2 + 1];
        float numRe = lRe - 1.0f, numIm = lIm;
        float den = aRe * aRe + aIm * aIm;
        float qRe = (numRe * aRe + numIm * aIm) / den;
        float qIm = (numIm * aRe - numRe * aIm) / den;
        float cnRe = C0 * qRe - C1 * qIm;
        float cnIm = C0 * qIm + C1 * qRe;
        Cn[ih * NN * 2 + 2 * n] = cnRe;
        Cn[ih * NN * 2 + 2 * n + 1] = cnIm;
        s_Cn[2 * n] = cnRe; s_Cn[2 * n + 1] = cnIm;
        // P[n][l] = lam^{l+1}
        for (int l = 0; l < TT; l++) {
            float p = (float)(l + 1);
            float ee = expf(p * dRe);
            float ss, cc; sincosf(p * dIm, &ss, &cc);
            P[(ih * NN + n) * TT * 2 + 2 * l]     = ee * cc;
            P[(ih * NN + n) * TT * 2 + 2 * l + 1] = ee * ss;
        }
    }
    __syncthreads();
    // Kt[d] = 2 * sum_n Re(Cn * lam^d), d = tid (0..63)
    int d = tid;
    float acc = 0.0f;
    for (int n = 0; n < NN; n++) {
        float dRe = s_dtA[2 * n], dIm = s_dtA[2 * n + 1];
        float ee = expf((float)d * dRe);
        float ss, cc; sincosf((float)d * dIm, &ss, &cc);
        acc += s_Cn[2 * n] * (ee * cc) - s_Cn[2 * n + 1] * (ee * ss);
    }
    Kt[ih * TT + d] = 2.0f * acc;
}

// ---------------------------------------------------------------- embed: u0 = x@W1^T + b1
__global__ __launch_bounds__(256) void embed_kernel(const float* __restrict__ x,
                             const float* __restrict__ W1, const float* __restrict__ b1,
                             float* __restrict__ u) {
    int idx = blockIdx.x * blockDim.x + threadIdx.x;
    if (idx >= BL) return;
    int b = idx / LL, l = idx - b * LL;
    float x0 = x[idx * 3], x1 = x[idx * 3 + 1], x2 = x[idx * 3 + 2];
    float u0 = fmaf(W1[0], x0, fmaf(W1[1], x1, fmaf(W1[2], x2, b1[0])));
    float u1 = fmaf(W1[3], x0, fmaf(W1[4], x1, fmaf(W1[5], x2, b1[1])));
    u[(b * HH + 0) * LL + l] = u0;
    u[(b * HH + 1) * LL + l] = u1;
}

// ---------------------------------------------------------------- phase A: chunk-local final states
__global__ __launch_bounds__(256) void phaseA_kernel(const float* __restrict__ u,
                              const float* __restrict__ lam,
                              float* __restrict__ st, int layer) {
    int gwave = (blockIdx.x * blockDim.x + threadIdx.x) >> 6;   // exactly B*CHK waves
    int lane = threadIdx.x & 63;
    int b = gwave / CHK, c = gwave - b * CHK;
    int h = lane >> 5, n = lane & 31;
    float lRe = lam[(layer * HH + h) * NN * 2 + 2 * n];
    float lIm = lam[(layer * HH + h) * NN * 2 + 2 * n + 1];
    const float* up = u + (b * HH + h) * LL + c * TT;
    int rem = LL - c * TT;
    int j0 = lane & 31;
    float uA = (j0 < rem) ? up[j0] : 0.0f;
    float uB = (32 + j0 < rem) ? up[32 + j0] : 0.0f;
    float sRe = 0.0f, sIm = 0.0f;
#pragma unroll
    for (int j = 0; j < TT; j++) {
        float src = (j < 32) ? uA : uB;
        float uv = __shfl(src, (lane & 32) | (j & 31), 64);
        float nRe = fmaf(lRe, sRe, fmaf(-lIm, sIm, uv));
        float nIm = fmaf(lRe, sIm, lIm * sRe);
        sRe = nRe; sIm = nIm;
    }
    st[(b * CHK + c) * 128 + lane] = sRe;
    st[(b * CHK + c) * 128 + 64 + lane] = sIm;
}

// ---------------------------------------------------------------- phase B: cross-chunk prefix scan (in place)
__global__ __launch_bounds__(256) void phaseB_kernel(const float* __restrict__ lamT,
                              float* __restrict__ st, int layer) {
    int t = blockIdx.x * blockDim.x + threadIdx.x;   // exactly B*64 threads
    int b = t >> 6, lane = t & 63;
    int h = lane >> 5, n = lane & 31;
    float lRe = lamT[(layer * HH + h) * NN * 2 + 2 * n];
    float lIm = lamT[(layer * HH + h) * NN * 2 + 2 * n + 1];
    float* base = st + (size_t)b * CHK * 128;
    float rRe = 0.0f, rIm = 0.0f;
    float nxRe = base[lane], nxIm = base[64 + lane];
    for (int c = 0; c < CHK; c++) {
        float sfRe = nxRe, sfIm = nxIm;
        if (c + 1 < CHK) {
            nxRe = base[(c + 1) * 128 + lane];
            nxIm = base[(c + 1) * 128 + 64 + lane];
        }
        base[c * 128 + lane] = rRe;
        base[c * 128 + 64 + lane] = rIm;
        float tRe = fmaf(lRe, rRe, fmaf(-lIm, rIm, sfRe));
        float tIm = fmaf(lRe, rIm, fmaf(lIm, rRe, sfIm));
        rRe = tRe; rIm = tIm;
    }
}

// ---------------------------------------------------------------- phase C v2: R=4 register tiling
// Each wave handles 4 consecutive chunks (256 timesteps). Lane = (g, li):
// g = lane>>4 selects chunk, li = lane&15; lane computes timesteps 4li..4li+3.
__global__ __launch_bounds__(256) void phaseC_kernel(const float* __restrict__ u,
                              float* __restrict__ uNext,
                              const float* __restrict__ Cn, const float* __restrict__ Kt,
                              const float* __restrict__ P, const float* __restrict__ st,
                              const float* __restrict__ Dp, const float* __restrict__ Wout,
                              const float* __restrict__ bout, int layer,
                              const float* __restrict__ W2, const float* __restrict__ b2,
                              float* __restrict__ finalOut) {
    const int wSlot = threadIdx.x >> 6;
    const int lane = threadIdx.x & 63;
    const int g = lane >> 4;
    const int li = lane & 15;
    int gwave = blockIdx.x * 4 + wSlot;          // 0 .. B*QG-1 (grid exact)
    int b = gwave / QG, q = gwave - b * QG;
    int c0 = q * 4;
    int l0q = c0 * TT;                           // q*256

    // LDS: zero-padded u image per chunk (group stride 131 -> <=2-way bank alias),
    // and w = Cn*s0 per chunk (group stride 130 -> conflict-free b64 reads).
    __shared__ float s_u[4][2][4 * 131];         // [wave][ch][g*131 + 0..127]
    __shared__ float s_w[4][4 * 130];            // [wave][g*130 + 2*(ch*32+n) + {0,1}]

    const float* ub = u + (size_t)b * HH * LL;
#pragma unroll
    for (int gg = 0; gg < 4; gg++) {
        int l = l0q + gg * TT + lane;
        float v0 = (l < LL) ? ub[l] : 0.0f;
        float v1 = (l < LL) ? ub[LL + l] : 0.0f;
        s_u[wSlot][0][gg * 131 + 64 + lane] = v0;
        s_u[wSlot][1][gg * 131 + 64 + lane] = v1;
        s_u[wSlot][0][gg * 131 + lane] = 0.0f;
        s_u[wSlot][1][gg * 131 + lane] = 0.0f;
    }
    {
        int chh = lane >> 5, n = lane & 31;
        float cnRe = Cn[(layer * HH + chh) * NN * 2 + 2 * n];
        float cnIm = Cn[(layer * HH + chh) * NN * 2 + 2 * n + 1];
#pragma unroll
        for (int gg = 0; gg < 4; gg++) {
            int c = c0 + gg; if (c > CHK - 1) c = CHK - 1;
            float s0Re = st[(b * CHK + c) * 128 + lane];
            float s0Im = st[(b * CHK + c) * 128 + 64 + lane];
            s_w[wSlot][gg * 130 + 2 * lane]     = cnRe * s0Re - cnIm * s0Im;
            s_w[wSlot][gg * 130 + 2 * lane + 1] = cnRe * s0Im + cnIm * s0Re;
        }
    }
    __syncthreads();

    const int c = c0 + g;
    const int t0 = 4 * li;

    // ---- correction: a[j] = sum_n Re(w_n * lam_n^{t0+j+1})
    const float* P0 = P + (size_t)(layer * HH) * NN * TT * 2;
    const float* wbase = &s_w[wSlot][g * 130];
    float a0[4] = {0.f, 0.f, 0.f, 0.f}, a1[4] = {0.f, 0.f, 0.f, 0.f};
#pragma unroll 8
    for (int nn = 0; nn < NN; nn++) {
        float2 w0 = *(const float2*)(wbase + 2 * nn);
        float2 w1 = *(const float2*)(wbase + 64 + 2 * nn);
        const float* p0 = P0 + (size_t)(nn * TT + t0) * 2;
        const float* p1 = p0 + (size_t)NN * TT * 2;
        float4 pa = *(const float4*)p0;
        float4 pb = *(const float4*)(p0 + 4);
        float4 pc = *(const float4*)p1;
        float4 pd = *(const float4*)(p1 + 4);
        a0[0] = fmaf(w0.x, pa.x, fmaf(-w0.y, pa.y, a0[0]));
        a0[1] = fmaf(w0.x, pa.z, fmaf(-w0.y, pa.w, a0[1]));
        a0[2] = fmaf(w0.x, pb.x, fmaf(-w0.y, pb.y, a0[2]));
        a0[3] = fmaf(w0.x, pb.z, fmaf(-w0.y, pb.w, a0[3]));
        a1[0] = fmaf(w1.x, pc.x, fmaf(-w1.y, pc.y, a1[0]));
        a1[1] = fmaf(w1.x, pc.z, fmaf(-w1.y, pc.w, a1[1]));
        a1[2] = fmaf(w1.x, pd.x, fmaf(-w1.y, pd.y, a1[2]));
        a1[3] = fmaf(w1.x, pd.z, fmaf(-w1.y, pd.w, a1[3]));
    }

    // ---- intra-chunk causal conv, sliding window, k via wave-uniform loads
    const float* k0 = Kt + (layer * HH) * TT;
    const float* k1 = k0 + TT;
    const float* su0 = &s_u[wSlot][0][g * 131 + 64];
    const float* su1 = &s_u[wSlot][1][g * 131 + 64];
    float win0[4], win1[4], u0s[4], u1s[4];
#pragma unroll
    for (int j = 0; j < 4; j++) {
        win0[j] = su0[t0 + j]; win1[j] = su1[t0 + j];
        u0s[j] = win0[j]; u1s[j] = win1[j];
    }
    float cv0[4] = {0.f, 0.f, 0.f, 0.f}, cv1[4] = {0.f, 0.f, 0.f, 0.f};
#pragma unroll
    for (int d = 0; d < TT; d++) {
        float kk0 = k0[d], kk1 = k1[d];
#pragma unroll
        for (int j = 0; j < 4; j++) {
            cv0[j] = fmaf(kk0, win0[j], cv0[j]);
            cv1[j] = fmaf(kk1, win1[j], cv1[j]);
        }
        if (d < TT - 1) {
#pragma unroll
            for (int j = 3; j > 0; j--) { win0[j] = win0[j - 1]; win1[j] = win1[j - 1]; }
            win0[0] = su0[t0 - d - 1];
            win1[0] = su1[t0 - d - 1];
        }
    }

    // ---- epilogue: D-skip, exact GELU, 1x1 conv mix, GLU (and final proj on last layer)
    float D0 = Dp[layer * HH + 0], D1 = Dp[layer * HH + 1];
    const float* Wo = Wout + layer * 8;
    const float* bo = bout + layer * 4;
    int lbase = c * TT + t0;
    bool valid = (c < CHK) && (lbase + 3 < LL);
    float r0[4], r1[4];
#pragma unroll
    for (int j = 0; j < 4; j++) {
        float y0 = fmaf(2.0f, a0[j], cv0[j]);
        float y1 = fmaf(2.0f, a1[j], cv1[j]);
        y0 = fmaf(D0, u0s[j], y0);
        y1 = fmaf(D1, u1s[j], y1);
        y0 = 0.5f * y0 * (1.0f + erff(y0 * 0.70710678118654752f));
        y1 = 0.5f * y1 * (1.0f + erff(y1 * 0.70710678118654752f));
        float z0 = fmaf(Wo[0], y0, fmaf(Wo[1], y1, bo[0]));
        float z1 = fmaf(Wo[2], y0, fmaf(Wo[3], y1, bo[1]));
        float z2 = fmaf(Wo[4], y0, fmaf(Wo[5], y1, bo[2]));
        float z3 = fmaf(Wo[6], y0, fmaf(Wo[7], y1, bo[3]));
        float g2 = 1.0f / (1.0f + expf(-z2));
        float g3 = 1.0f / (1.0f + expf(-z3));
        r0[j] = z0 * g2;
        r1[j] = z1 * g3;
    }
    if (layer != NL - 1) {
        if (valid) {
            *(float4*)(uNext + (size_t)b * HH * LL + lbase) =
                make_float4(r0[0], r0[1], r0[2], r0[3]);
            *(float4*)(uNext + (size_t)b * HH * LL + LL + lbase) =
                make_float4(r1[0], r1[1], r1[2], r1[3]);
        }
    } else {
        if (valid) {
            float o[8];
#pragma unroll
            for (int j = 0; j < 4; j++) {
                o[2 * j]     = fmaf(r0[j], W2[0], fmaf(r1[j], W2[1], b2[0]));
                o[2 * j + 1] = fmaf(r0[j], W2[2], fmaf(r1[j], W2[3], b2[1]));
            }
            float* op = finalOut + ((size_t)b * LL + lbase) * 2;
            *(float4*)op       = make_float4(o[0], o[1], o[2], o[3]);
            *(float4*)(op + 4) = make_float4(o[4], o[5], o[6], o[7]);
        }
    }
}

extern "C" void kernel_launch(void* const* d_in, const int* in_sizes, int n_in,
                              void* d_out, int out_size, void* d_ws, size_t ws_size,
                              hipStream_t stream) {
    const float* x         = (const float*)d_in[0];
    const float* W1        = (const float*)d_in[1];
    const float* b1        = (const float*)d_in[2];
    const float* W2        = (const float*)d_in[3];
    const float* b2        = (const float*)d_in[4];
    const float* log_dt    = (const float*)d_in[5];
    const float* log_A_real= (const float*)d_in[6];
    const float* A_imag    = (const float*)d_in[7];
    const float* Cin       = (const float*)d_in[8];
    const float* Dp        = (const float*)d_in[9];
    const float* Wout      = (const float*)d_in[10];
    const float* bout      = (const float*)d_in[11];
    float* out = (float*)d_out;
    float* ws = (float*)d_ws;

    float* U0   = ws + OFF_U0;
    float* U1   = ws + OFF_U1;
    float* ST   = ws + OFF_ST;
    float* lam  = ws + OFF_TAB;
    float* lamT = lam + 512;
    float* Cn   = lamT + 512;
    float* Kt   = Cn + 512;
    float* P    = Kt + 512;

    setup_kernel<<<dim3(NL * HH), dim3(64), 0, stream>>>(log_dt, log_A_real, A_imag, Cin,
                                                         lam, lamT, Cn, Kt, P);
    embed_kernel<<<dim3(BL / 256), dim3(256), 0, stream>>>(x, W1, b1, U0);

    float* cur = U0;
    float* nxt = U1;
    for (int i = 0; i < NL; i++) {
        phaseA_kernel<<<dim3(BB * CHK / 4), dim3(256), 0, stream>>>(cur, lam, ST, i);
        phaseB_kernel<<<dim3(BB * 64 / 256), dim3(256), 0, stream>>>(lamT, ST, i);
        phaseC_kernel<<<dim3(BB * QG / 4), dim3(256), 0, stream>>>(cur, nxt, Cn, Kt, P, ST,
                                                                   Dp, Wout, bout, i,
                                                                   W2, b2, out);
        float* tmp = cur; cur = nxt; nxt = tmp;
    }
}

// Round 3
// 695.990 us; speedup vs baseline: 1.5336x; 1.3905x over previous
//
#include <hip/hip_runtime.h>
#include <hip/hip_bf16.h>
#include <math.h>

// Problem constants
#define BB 512
#define LL 10000
#define HH 2
#define NN 32
#define NL 4
#define TT 64
#define CHK 157           // ceil(10000/64)
#define CPAD 160          // padded chunks per sequence (multiple of 16)
#define BL (BB*LL)        // 5,120,000

// Workspace layout (in floats)
#define OFF_U0   0
#define OFF_U1   10240000          // B*H*L
#define OFF_ST   20480000          // B*CHK*128 = 10,289,152
#define OFF_TAB  30769152
// tables: lam 512 | lamT 512 | Cn 512 | Kt 512 | P 32768 | AF 65536 (131072 halves)

typedef _Float16 half8 __attribute__((ext_vector_type(8)));
typedef float f32x4 __attribute__((ext_vector_type(4)));

// ---------------------------------------------------------------- setup 1: scalar tables
__global__ void setup_kernel(const float* __restrict__ log_dt,
                             const float* __restrict__ log_A_real,
                             const float* __restrict__ A_imag,
                             const float* __restrict__ Cin,
                             float* __restrict__ lam, float* __restrict__ lamT,
                             float* __restrict__ Cn, float* __restrict__ Kt,
                             float* __restrict__ P) {
    int ih = blockIdx.x;          // 0..7 = layer*H + h
    int tid = threadIdx.x;        // 0..63
    __shared__ float s_dtA[NN * 2];
    __shared__ float s_Cn[NN * 2];
    float dt = expf(log_dt[ih]);
    if (tid < NN) {
        int n = tid;
        float aRe = -expf(log_A_real[ih * NN + n]);
        float aIm = A_imag[ih * NN + n];
        float dRe = aRe * dt, dIm = aIm * dt;
        s_dtA[2 * n] = dRe; s_dtA[2 * n + 1] = dIm;
        float e = expf(dRe);
        float sn, cs; sincosf(dIm, &sn, &cs);
        float lRe = e * cs, lIm = e * sn;
        lam[ih * NN * 2 + 2 * n] = lRe;
        lam[ih * NN * 2 + 2 * n + 1] = lIm;
        float eT = expf((float)TT * dRe);
        float snT, csT; sincosf((float)TT * dIm, &snT, &csT);
        lamT[ih * NN * 2 + 2 * n] = eT * csT;
        lamT[ih * NN * 2 + 2 * n + 1] = eT * snT;
        // Cn = (C0 + i C1) * (lam - 1) / A
        float C0 = Cin[(ih * NN + n) * 2];
        float C1 = Cin[(ih * NN + n) * 2 + 1];
        float numRe = lRe - 1.0f, numIm = lIm;
        float den = aRe * aRe + aIm * aIm;
        float qRe = (numRe * aRe + numIm * aIm) / den;
        float qIm = (numIm * aRe - numRe * aIm) / den;
        float cnRe = C0 * qRe - C1 * qIm;
        float cnIm = C0 * qIm + C1 * qRe;
        Cn[ih * NN * 2 + 2 * n] = cnRe;
        Cn[ih * NN * 2 + 2 * n + 1] = cnIm;
        s_Cn[2 * n] = cnRe; s_Cn[2 * n + 1] = cnIm;
        // P[n][l] = lam^{l+1}
        for (int l = 0; l < TT; l++) {
            float p = (float)(l + 1);
            float ee = expf(p * dRe);
            float ss, cc; sincosf(p * dIm, &ss, &cc);
            P[(ih * NN + n) * TT * 2 + 2 * l]     = ee * cc;
            P[(ih * NN + n) * TT * 2 + 2 * l + 1] = ee * ss;
        }
    }
    __syncthreads();
    // Kt[d] = 2 * sum_n Re(Cn * lam^d), d = tid (0..63)
    int d = tid;
    float acc = 0.0f;
    for (int n = 0; n < NN; n++) {
        float dRe = s_dtA[2 * n], dIm = s_dtA[2 * n + 1];
        float ee = expf((float)d * dRe);
        float ss, cc; sincosf((float)d * dIm, &ss, &cc);
        acc += s_Cn[2 * n] * (ee * cc) - s_Cn[2 * n + 1] * (ee * ss);
    }
    Kt[ih * TT + d] = 2.0f * acc;
}

// ---------------------------------------------------------------- setup 2: A-fragments (fp16 hi/lo)
// A = [T | P'] (64 x 128) per (layer,ch).  T[l,k] = Kt[l-k] (k<=l).
// P'[l,64+2n] = 2*Re(lam^{l+1}), P'[l,64+2n+1] = -2*Im(lam^{l+1}).
// Stored in MFMA A-fragment layout for 16x16x32: element (lane, j) of frag
// (kt,lt) is A[lt*16 + (lane&15)][kt*32 + (lane>>4)*8 + j].
// AF[ih][split][kt][lt][lane][j], halves.
__global__ void setup2_kernel(const float* __restrict__ Kt,
                              const float* __restrict__ P,
                              _Float16* __restrict__ AF) {
    int ih = blockIdx.x;       // layer*2+ch
    int lane = threadIdx.x;    // 0..63
    for (int kt = 0; kt < 4; kt++) {
        for (int lt = 0; lt < 4; lt++) {
            int l = lt * 16 + (lane & 15);
            int kbase = kt * 32 + (lane >> 4) * 8;
            for (int j = 0; j < 8; j++) {
                int k = kbase + j;
                float v;
                if (k < 64) {
                    int d = l - k;
                    v = (d >= 0) ? Kt[ih * TT + d] : 0.0f;
                } else {
                    int j2 = k - 64;
                    int n = j2 >> 1;
                    float pre = P[(ih * NN + n) * TT * 2 + 2 * l];
                    float pim = P[(ih * NN + n) * TT * 2 + 2 * l + 1];
                    v = (j2 & 1) ? (-2.0f * pim) : (2.0f * pre);
                }
                float hi = __uint_as_float(__float_as_uint(v) & 0xFFFFE000u);
                float lo = v - hi;
                size_t o0 = ((((size_t)ih * 2 + 0) * 4 + kt) * 4 + lt) * 512 + lane * 8 + j;
                size_t o1 = ((((size_t)ih * 2 + 1) * 4 + kt) * 4 + lt) * 512 + lane * 8 + j;
                AF[o0] = (_Float16)hi;
                AF[o1] = (_Float16)lo;
            }
        }
    }
}

// ---------------------------------------------------------------- embed: u0 = x@W1^T + b1
__global__ __launch_bounds__(256) void embed_kernel(const float* __restrict__ x,
                             const float* __restrict__ W1, const float* __restrict__ b1,
                             float* __restrict__ u) {
    int idx = blockIdx.x * blockDim.x + threadIdx.x;
    if (idx >= BL) return;
    int b = idx / LL, l = idx - b * LL;
    float x0 = x[idx * 3], x1 = x[idx * 3 + 1], x2 = x[idx * 3 + 2];
    float u0 = fmaf(W1[0], x0, fmaf(W1[1], x1, fmaf(W1[2], x2, b1[0])));
    float u1 = fmaf(W1[3], x0, fmaf(W1[4], x1, fmaf(W1[5], x2, b1[1])));
    u[(b * HH + 0) * LL + l] = u0;
    u[(b * HH + 1) * LL + l] = u1;
}

// ---------------------------------------------------------------- phase A: chunk-local final states
__global__ __launch_bounds__(256) void phaseA_kernel(const float* __restrict__ u,
                              const float* __restrict__ lam,
                              float* __restrict__ st, int layer) {
    int gwave = (blockIdx.x * blockDim.x + threadIdx.x) >> 6;   // exactly B*CHK waves
    int lane = threadIdx.x & 63;
    int b = gwave / CHK, c = gwave - b * CHK;
    int h = lane >> 5, n = lane & 31;
    float lRe = lam[(layer * HH + h) * NN * 2 + 2 * n];
    float lIm = lam[(layer * HH + h) * NN * 2 + 2 * n + 1];
    const float* up = u + (b * HH + h) * LL + c * TT;
    int rem = LL - c * TT;
    int j0 = lane & 31;
    float uA = (j0 < rem) ? up[j0] : 0.0f;
    float uB = (32 + j0 < rem) ? up[32 + j0] : 0.0f;
    float sRe = 0.0f, sIm = 0.0f;
#pragma unroll
    for (int j = 0; j < TT; j++) {
        float src = (j < 32) ? uA : uB;
        float uv = __shfl(src, (lane & 32) | (j & 31), 64);
        float nRe = fmaf(lRe, sRe, fmaf(-lIm, sIm, uv));
        float nIm = fmaf(lRe, sIm, lIm * sRe);
        sRe = nRe; sIm = nIm;
    }
    st[(b * CHK + c) * 128 + lane] = sRe;
    st[(b * CHK + c) * 128 + 64 + lane] = sIm;
}

// ---------------------------------------------------------------- phase B: cross-chunk scan + fold Cn
// In-place: record c (raw chunk-final states, layout [h*32+n | 64 + h*32+n])
// is replaced by w = Cn * (entering state), interleaved: [h*64 + 2n, h*64+2n+1].
__global__ __launch_bounds__(256) void phaseB_kernel(const float* __restrict__ lamT,
                              const float* __restrict__ CnT,
                              float* __restrict__ st, int layer) {
    int t = blockIdx.x * blockDim.x + threadIdx.x;   // exactly B*64 threads
    int b = t >> 6, lane = t & 63;
    int h = lane >> 5, n = lane & 31;
    float lRe = lamT[(layer * HH + h) * NN * 2 + 2 * n];
    float lIm = lamT[(layer * HH + h) * NN * 2 + 2 * n + 1];
    float cnRe = CnT[(layer * HH + h) * NN * 2 + 2 * n];
    float cnIm = CnT[(layer * HH + h) * NN * 2 + 2 * n + 1];
    float* base = st + (size_t)b * CHK * 128;
    float rRe = 0.0f, rIm = 0.0f;
    float nxRe = base[lane], nxIm = base[64 + lane];
    for (int c = 0; c < CHK; c++) {
        float sfRe = nxRe, sfIm = nxIm;
        if (c + 1 < CHK) {
            nxRe = base[(c + 1) * 128 + lane];
            nxIm = base[(c + 1) * 128 + 64 + lane];
        }
        float wRe = cnRe * rRe - cnIm * rIm;
        float wIm = cnRe * rIm + cnIm * rRe;
        float2 wv = make_float2(wRe, wIm);
        *(float2*)(base + c * 128 + h * 64 + 2 * n) = wv;
        float tRe = fmaf(lRe, rRe, fmaf(-lIm, rIm, sfRe));
        float tIm = fmaf(lRe, rIm, fmaf(lIm, rRe, sfIm));
        rRe = tRe; rIm = tIm;
    }
}

// ---------------------------------------------------------------- phase C: MFMA GEMM + fused epilogue
// Y(64 x M) = [T|P'] (64x128) x [u;w] (128xM) per channel, fp16 hi/lo split,
// fp32 accumulate. Wave = 32 columns (2 n-tiles), both channels, 64 l-rows.
__global__ __launch_bounds__(256) void phaseC_mfma(
        const float* __restrict__ u, float* __restrict__ uNext,
        const _Float16* __restrict__ AF, const float* __restrict__ st,
        const float* __restrict__ Dp, const float* __restrict__ Wout,
        const float* __restrict__ bout, int layer,
        const float* __restrict__ W2, const float* __restrict__ b2,
        float* __restrict__ out, int isLast) {
    const int wv = threadIdx.x >> 6;
    const int lane = threadIdx.x & 63;
    const int quad = lane >> 4;
    const int li = lane & 15;
    const int gw = blockIdx.x * 4 + wv;        // 0..2559
    const int colg0 = gw * 32;

    const float* uB[2];
    const float* wB[2];
    int cArr[2], bArr[2];
#pragma unroll
    for (int nt = 0; nt < 2; nt++) {
        int colp = colg0 + nt * 16 + li;
        int b = colp / CPAD;
        int c = colp - b * CPAD;
        cArr[nt] = c; bArr[nt] = b;
        int cc = (c < CHK - 1) ? c : (CHK - 1);
        uB[nt] = u + (size_t)(b * HH) * LL + cc * TT;
        wB[nt] = st + ((size_t)b * CHK + cc) * 128;
    }

    f32x4 acc[4][2][2];   // [lt][nt][ch]
#pragma unroll
    for (int lt = 0; lt < 4; lt++)
#pragma unroll
        for (int nt = 0; nt < 2; nt++)
#pragma unroll
            for (int ch = 0; ch < 2; ch++)
                acc[lt][nt][ch] = (f32x4){0.f, 0.f, 0.f, 0.f};

    const _Float16* AFl = AF + (size_t)layer * 32768;   // 2ch*2split*4kt*4lt*512

#pragma unroll
    for (int kt = 0; kt < 4; kt++) {
#pragma unroll
        for (int ch = 0; ch < 2; ch++) {
            const _Float16* afb = AFl + (((size_t)(ch * 2) * 4 + kt) * 4) * 512 + lane * 8;
            half8 Ah[4], Al[4];
#pragma unroll
            for (int lt = 0; lt < 4; lt++) {
                Ah[lt] = *(const half8*)(afb + lt * 512);
                Al[lt] = *(const half8*)(afb + 8192 + lt * 512);
            }
#pragma unroll
            for (int nt = 0; nt < 2; nt++) {
                const float* src = (kt < 2)
                    ? (uB[nt] + ch * LL + kt * 32 + quad * 8)
                    : (wB[nt] + ch * 64 + (kt - 2) * 32 + quad * 8);
                f32x4 f0 = *(const f32x4*)src;
                f32x4 f1 = *(const f32x4*)(src + 4);
                half8 Bh, Bl;
#pragma unroll
                for (int e = 0; e < 8; e++) {
                    float v = (e < 4) ? f0[e] : f1[e - 4];
                    float hi = __uint_as_float(__float_as_uint(v) & 0xFFFFE000u);
                    Bh[e] = (_Float16)hi;
                    Bl[e] = (_Float16)(v - hi);
                }
#pragma unroll
                for (int lt = 0; lt < 4; lt++) {
                    acc[lt][nt][ch] = __builtin_amdgcn_mfma_f32_16x16x32_f16(
                        Ah[lt], Bh, acc[lt][nt][ch], 0, 0, 0);
                    acc[lt][nt][ch] = __builtin_amdgcn_mfma_f32_16x16x32_f16(
                        Ah[lt], Bl, acc[lt][nt][ch], 0, 0, 0);
                    acc[lt][nt][ch] = __builtin_amdgcn_mfma_f32_16x16x32_f16(
                        Al[lt], Bh, acc[lt][nt][ch], 0, 0, 0);
                }
            }
        }
    }

    // ---- fused epilogue
    float D0 = Dp[layer * HH + 0], D1 = Dp[layer * HH + 1];
    const float* Wo = Wout + layer * 8;
    const float* bo = bout + layer * 4;
    float w20 = W2[0], w21 = W2[1], w22 = W2[2], w23 = W2[3];
    float b20 = b2[0], b21 = b2[1];

#pragma unroll
    for (int nt = 0; nt < 2; nt++) {
        int c = cArr[nt];
        bool cOK = (c < CHK);
#pragma unroll
        for (int lt = 0; lt < 4; lt++) {
            int l = lt * 16 + quad * 4;
            f32x4 u0 = *(const f32x4*)(uB[nt] + l);
            f32x4 u1 = *(const f32x4*)(uB[nt] + LL + l);
            f32x4 y0 = acc[lt][nt][0], y1 = acc[lt][nt][1];
            f32x4 r0, r1;
#pragma unroll
            for (int r = 0; r < 4; r++) {
                float a0 = fmaf(D0, u0[r], y0[r]);
                float a1 = fmaf(D1, u1[r], y1[r]);
                a0 = 0.5f * a0 * (1.0f + erff(a0 * 0.70710678118654752f));
                a1 = 0.5f * a1 * (1.0f + erff(a1 * 0.70710678118654752f));
                float z0 = fmaf(Wo[0], a0, fmaf(Wo[1], a1, bo[0]));
                float z1 = fmaf(Wo[2], a0, fmaf(Wo[3], a1, bo[1]));
                float z2 = fmaf(Wo[4], a0, fmaf(Wo[5], a1, bo[2]));
                float z3 = fmaf(Wo[6], a0, fmaf(Wo[7], a1, bo[3]));
                float g2 = 1.0f / (1.0f + expf(-z2));
                float g3 = 1.0f / (1.0f + expf(-z3));
                r0[r] = z0 * g2;
                r1[r] = z1 * g3;
            }
            bool ok = cOK && (c < CHK - 1 || lt == 0);
            if (!isLast) {
                if (ok) {
                    float* p0 = uNext + (uB[nt] - u) + l;
                    *(f32x4*)p0 = r0;
                    *(f32x4*)(p0 + LL) = r1;
                }
            } else {
                if (ok) {
                    float* op = out + ((size_t)bArr[nt] * LL + (size_t)c * TT + l) * 2;
                    f32x4 lo4, hi4;
                    lo4[0] = fmaf(r0[0], w20, fmaf(r1[0], w21, b20));
                    lo4[1] = fmaf(r0[0], w22, fmaf(r1[0], w23, b21));
                    lo4[2] = fmaf(r0[1], w20, fmaf(r1[1], w21, b20));
                    lo4[3] = fmaf(r0[1], w22, fmaf(r1[1], w23, b21));
                    hi4[0] = fmaf(r0[2], w20, fmaf(r1[2], w21, b20));
                    hi4[1] = fmaf(r0[2], w22, fmaf(r1[2], w23, b21));
                    hi4[2] = fmaf(r0[3], w20, fmaf(r1[3], w21, b20));
                    hi4[3] = fmaf(r0[3], w22, fmaf(r1[3], w23, b21));
                    *(f32x4*)op = lo4;
                    *(f32x4*)(op + 4) = hi4;
                }
            }
        }
    }
}

extern "C" void kernel_launch(void* const* d_in, const int* in_sizes, int n_in,
                              void* d_out, int out_size, void* d_ws, size_t ws_size,
                              hipStream_t stream) {
    const float* x         = (const float*)d_in[0];
    const float* W1        = (const float*)d_in[1];
    const float* b1        = (const float*)d_in[2];
    const float* W2        = (const float*)d_in[3];
    const float* b2        = (const float*)d_in[4];
    const float* log_dt    = (const float*)d_in[5];
    const float* log_A_real= (const float*)d_in[6];
    const float* A_imag    = (const float*)d_in[7];
    const float* Cin       = (const float*)d_in[8];
    const float* Dp        = (const float*)d_in[9];
    const float* Wout      = (const float*)d_in[10];
    const float* bout      = (const float*)d_in[11];
    float* out = (float*)d_out;
    float* ws = (float*)d_ws;

    float* U0   = ws + OFF_U0;
    float* U1   = ws + OFF_U1;
    float* ST   = ws + OFF_ST;
    float* lam  = ws + OFF_TAB;
    float* lamT = lam + 512;
    float* Cn   = lamT + 512;
    float* Kt   = Cn + 512;
    float* P    = Kt + 512;
    _Float16* AF = (_Float16*)(P + 32768);

    setup_kernel<<<dim3(NL * HH), dim3(64), 0, stream>>>(log_dt, log_A_real, A_imag, Cin,
                                                         lam, lamT, Cn, Kt, P);
    setup2_kernel<<<dim3(NL * HH), dim3(64), 0, stream>>>(Kt, P, AF);
    embed_kernel<<<dim3(BL / 256), dim3(256), 0, stream>>>(x, W1, b1, U0);

    float* cur = U0;
    float* nxt = U1;
    for (int i = 0; i < NL; i++) {
        phaseA_kernel<<<dim3(BB * CHK / 4), dim3(256), 0, stream>>>(cur, lam, ST, i);
        phaseB_kernel<<<dim3(BB * 64 / 256), dim3(256), 0, stream>>>(lamT, Cn, ST, i);
        phaseC_mfma<<<dim3(BB * CPAD / 128), dim3(256), 0, stream>>>(cur, nxt, AF, ST,
                                                                     Dp, Wout, bout, i,
                                                                     W2, b2, out,
                                                                     (i == NL - 1) ? 1 : 0);
        float* tmp = cur; cur = nxt; nxt = tmp;
    }
}

// Round 4
// 438.811 us; speedup vs baseline: 2.4324x; 1.5861x over previous
//
#include <hip/hip_runtime.h>
#include <hip/hip_bf16.h>
#include <math.h>

// Problem constants
#define BB 512
#define LL 10000
#define HH 2
#define NN 32
#define NL 4
#define TT 64
#define CHK 157           // ceil(10000/64)
#define CPAD 160          // padded chunks per sequence (multiple of 16)
#define BL (BB*LL)        // 5,120,000

// Workspace layout (in floats)
#define OFF_U0   0
#define OFF_U1   10240000          // B*H*L
#define OFF_S0   20480000          // raw states: B*CHK*128 = 10,289,152
#define OFF_S1   30769152          // w buffer  : B*CHK*128
#define OFF_TAB  41058304
// tables: lam 512 | lamT 512 | Cn 512 | Kt 512 | P 32768 | AF 131072h | EF 65536h

typedef _Float16 half8 __attribute__((ext_vector_type(8)));
typedef float f32x4 __attribute__((ext_vector_type(4)));

// ---------------------------------------------------------------- setup 1: scalar tables
__global__ void setup_kernel(const float* __restrict__ log_dt,
                             const float* __restrict__ log_A_real,
                             const float* __restrict__ A_imag,
                             const float* __restrict__ Cin,
                             float* __restrict__ lam, float* __restrict__ lamT,
                             float* __restrict__ Cn, float* __restrict__ Kt,
                             float* __restrict__ P) {
    int ih = blockIdx.x;          // 0..7 = layer*H + h
    int tid = threadIdx.x;        // 0..63
    __shared__ float s_dtA[NN * 2];
    __shared__ float s_Cn[NN * 2];
    float dt = expf(log_dt[ih]);
    if (tid < NN) {
        int n = tid;
        float aRe = -expf(log_A_real[ih * NN + n]);
        float aIm = A_imag[ih * NN + n];
        float dRe = aRe * dt, dIm = aIm * dt;
        s_dtA[2 * n] = dRe; s_dtA[2 * n + 1] = dIm;
        float e = expf(dRe);
        float sn, cs; sincosf(dIm, &sn, &cs);
        float lRe = e * cs, lIm = e * sn;
        lam[ih * NN * 2 + 2 * n] = lRe;
        lam[ih * NN * 2 + 2 * n + 1] = lIm;
        float eT = expf((float)TT * dRe);
        float snT, csT; sincosf((float)TT * dIm, &snT, &csT);
        lamT[ih * NN * 2 + 2 * n] = eT * csT;
        lamT[ih * NN * 2 + 2 * n + 1] = eT * snT;
        // Cn = (C0 + i C1) * (lam - 1) / A
        float C0 = Cin[(ih * NN + n) * 2];
        float C1 = Cin[(ih * NN + n) * 2 + 1];
        float numRe = lRe - 1.0f, numIm = lIm;
        float den = aRe * aRe + aIm * aIm;
        float qRe = (numRe * aRe + numIm * aIm) / den;
        float qIm = (numIm * aRe - numRe * aIm) / den;
        float cnRe = C0 * qRe - C1 * qIm;
        float cnIm = C0 * qIm + C1 * qRe;
        Cn[ih * NN * 2 + 2 * n] = cnRe;
        Cn[ih * NN * 2 + 2 * n + 1] = cnIm;
        s_Cn[2 * n] = cnRe; s_Cn[2 * n + 1] = cnIm;
        // P[n][l] = lam^{l+1}, l = 0..63
        for (int l = 0; l < TT; l++) {
            float p = (float)(l + 1);
            float ee = expf(p * dRe);
            float ss, cc; sincosf(p * dIm, &ss, &cc);
            P[(ih * NN + n) * TT * 2 + 2 * l]     = ee * cc;
            P[(ih * NN + n) * TT * 2 + 2 * l + 1] = ee * ss;
        }
    }
    __syncthreads();
    // Kt[d] = 2 * sum_n Re(Cn * lam^d), d = tid (0..63)
    int d = tid;
    float acc = 0.0f;
    for (int n = 0; n < NN; n++) {
        float dRe = s_dtA[2 * n], dIm = s_dtA[2 * n + 1];
        float ee = expf((float)d * dRe);
        float ss, cc; sincosf((float)d * dIm, &ss, &cc);
        acc += s_Cn[2 * n] * (ee * cc) - s_Cn[2 * n + 1] * (ee * ss);
    }
    Kt[ih * TT + d] = 2.0f * acc;
}

// ---------------------------------------------------------------- setup 2: A-fragments (fp16 hi/lo)
// AF: Y-GEMM A = [T | P'] (64x128) per (layer,ch); layout
//   AF[(((ih*2+split)*4 + kt)*4 + lt)*512 + lane*8 + j]
// EF: state-GEMM E (64x64): E[2n][j]=Re(lam_n^{63-j}), E[2n+1][j]=Im(lam_n^{63-j});
//   EF[(((ih*2+split)*2 + kt)*4 + lt)*512 + lane*8 + j]
__global__ void setup2_kernel(const float* __restrict__ Kt,
                              const float* __restrict__ P,
                              _Float16* __restrict__ AF,
                              _Float16* __restrict__ EF) {
    int ih = blockIdx.x;       // layer*2+ch
    int lane = threadIdx.x;    // 0..63
    for (int kt = 0; kt < 4; kt++) {
        for (int lt = 0; lt < 4; lt++) {
            int l = lt * 16 + (lane & 15);
            int kbase = kt * 32 + (lane >> 4) * 8;
            for (int j = 0; j < 8; j++) {
                int k = kbase + j;
                float v;
                if (k < 64) {
                    int d = l - k;
                    v = (d >= 0) ? Kt[ih * TT + d] : 0.0f;
                } else {
                    int j2 = k - 64;
                    int n = j2 >> 1;
                    float pre = P[(ih * NN + n) * TT * 2 + 2 * l];
                    float pim = P[(ih * NN + n) * TT * 2 + 2 * l + 1];
                    v = (j2 & 1) ? (-2.0f * pim) : (2.0f * pre);
                }
                float hi = __uint_as_float(__float_as_uint(v) & 0xFFFFE000u);
                float lo = v - hi;
                size_t o0 = ((((size_t)ih * 2 + 0) * 4 + kt) * 4 + lt) * 512 + lane * 8 + j;
                size_t o1 = ((((size_t)ih * 2 + 1) * 4 + kt) * 4 + lt) * 512 + lane * 8 + j;
                AF[o0] = (_Float16)hi;
                AF[o1] = (_Float16)lo;
            }
        }
    }
    for (int kt = 0; kt < 2; kt++) {
        for (int lt = 0; lt < 4; lt++) {
            int row = lt * 16 + (lane & 15);
            int n = row >> 1, isIm = row & 1;
            int kbase = kt * 32 + (lane >> 4) * 8;
            for (int j = 0; j < 8; j++) {
                int k = kbase + j;        // timestep 0..63
                int pw = 63 - k;          // power of lambda
                float v;
                if (pw == 0) v = isIm ? 0.0f : 1.0f;
                else v = P[(ih * NN + n) * TT * 2 + 2 * (pw - 1) + isIm];
                float hi = __uint_as_float(__float_as_uint(v) & 0xFFFFE000u);
                float lo = v - hi;
                size_t o0 = ((((size_t)ih * 2 + 0) * 2 + kt) * 4 + lt) * 512 + lane * 8 + j;
                size_t o1 = ((((size_t)ih * 2 + 1) * 2 + kt) * 4 + lt) * 512 + lane * 8 + j;
                EF[o0] = (_Float16)hi;
                EF[o1] = (_Float16)lo;
            }
        }
    }
}

// ---------------------------------------------------------------- embed: u0 = x@W1^T + b1
__global__ __launch_bounds__(256) void embed_kernel(const float* __restrict__ x,
                             const float* __restrict__ W1, const float* __restrict__ b1,
                             float* __restrict__ u) {
    int idx = blockIdx.x * blockDim.x + threadIdx.x;
    if (idx >= BL) return;
    int b = idx / LL, l = idx - b * LL;
    float x0 = x[idx * 3], x1 = x[idx * 3 + 1], x2 = x[idx * 3 + 2];
    float u0 = fmaf(W1[0], x0, fmaf(W1[1], x1, fmaf(W1[2], x2, b1[0])));
    float u1 = fmaf(W1[3], x0, fmaf(W1[4], x1, fmaf(W1[5], x2, b1[1])));
    u[(b * HH + 0) * LL + l] = u0;
    u[(b * HH + 1) * LL + l] = u1;
}

__device__ __forceinline__ void splitB(const f32x4& f0, const f32x4& f1,
                                       half8& Bh, half8& Bl) {
#pragma unroll
    for (int e = 0; e < 8; e++) {
        float v = (e < 4) ? f0[e] : f1[e - 4];
        float hi = __uint_as_float(__float_as_uint(v) & 0xFFFFE000u);
        Bh[e] = (_Float16)hi;
        Bl[e] = (_Float16)(v - hi);
    }
}

// ---------------------------------------------------------------- phase A (layer 0 only): states via MFMA
__global__ __launch_bounds__(256) void phaseA_mfma(const float* __restrict__ u,
                              const _Float16* __restrict__ EF,
                              float* __restrict__ stRaw) {
    const int wv = threadIdx.x >> 6;
    const int lane = threadIdx.x & 63;
    const int quad = lane >> 4;
    const int li = lane & 15;
    const int gw = blockIdx.x * 4 + wv;
    const int col = gw * 16 + li;
    const int b = col / CPAD;
    const int c = col - b * CPAD;
    const int cc = (c < CHK) ? c : (CHK - 1);
    const float* uB = u + (size_t)(b * HH) * LL + cc * TT;

    f32x4 eacc[4][2];
#pragma unroll
    for (int lt = 0; lt < 4; lt++)
#pragma unroll
        for (int ch = 0; ch < 2; ch++) eacc[lt][ch] = (f32x4){0.f, 0.f, 0.f, 0.f};

#pragma unroll
    for (int ch = 0; ch < 2; ch++) {
#pragma unroll
        for (int kt = 0; kt < 2; kt++) {
            const float* src = uB + ch * LL + kt * 32 + quad * 8;
            f32x4 f0 = *(const f32x4*)src;
            f32x4 f1 = *(const f32x4*)(src + 4);
            half8 Bh, Bl; splitB(f0, f1, Bh, Bl);
            const _Float16* efb = EF + (size_t)ch * 8192 + kt * 2048 + lane * 8;
#pragma unroll
            for (int lt = 0; lt < 4; lt++) {
                half8 Eh = *(const half8*)(efb + lt * 512);
                half8 El = *(const half8*)(efb + 4096 + lt * 512);
                eacc[lt][ch] = __builtin_amdgcn_mfma_f32_16x16x32_f16(Eh, Bh, eacc[lt][ch], 0, 0, 0);
                eacc[lt][ch] = __builtin_amdgcn_mfma_f32_16x16x32_f16(Eh, Bl, eacc[lt][ch], 0, 0, 0);
                eacc[lt][ch] = __builtin_amdgcn_mfma_f32_16x16x32_f16(El, Bh, eacc[lt][ch], 0, 0, 0);
            }
        }
    }
    if (c < CHK) {
        float* sp = stRaw + ((size_t)b * CHK + c) * 128;
#pragma unroll
        for (int ch = 0; ch < 2; ch++)
#pragma unroll
            for (int lt = 0; lt < 4; lt++)
                *(f32x4*)(sp + ch * 64 + lt * 16 + quad * 4) = eacc[lt][ch];
    }
}

// ---------------------------------------------------------------- phase B: cross-chunk scan, 8-deep prefetch
// stRaw record: [ch*64 + 2n + {0,1}] = Re/Im of chunk-final state.
// stW   record: [ch*64 + 2n + {0,1}] = w = Cn * (state entering chunk).
__global__ __launch_bounds__(64) void phaseB_kernel(const float* __restrict__ lamT,
                              const float* __restrict__ CnT,
                              const float* __restrict__ stRaw,
                              float* __restrict__ stW, int layer) {
    int b = blockIdx.x;
    int lane = threadIdx.x;
    int h = lane >> 5, n = lane & 31;
    float lRe = lamT[(layer * HH + h) * NN * 2 + 2 * n];
    float lIm = lamT[(layer * HH + h) * NN * 2 + 2 * n + 1];
    float cRe = CnT[(layer * HH + h) * NN * 2 + 2 * n];
    float cIm = CnT[(layer * HH + h) * NN * 2 + 2 * n + 1];
    const float2* src = (const float2*)(stRaw + (size_t)b * CHK * 128) + lane;
    float2* dst = (float2*)(stW + (size_t)b * CHK * 128) + lane;
    float2 buf[8];
#pragma unroll
    for (int p = 0; p < 8; p++) buf[p] = src[(size_t)p * 64];
    float rRe = 0.f, rIm = 0.f;
    for (int co = 0; co < 20; co++) {
#pragma unroll
        for (int ci = 0; ci < 8; ci++) {
            int cx = co * 8 + ci;
            if (cx < CHK) {
                float2 v = buf[ci];
                if (cx + 8 < CHK) buf[ci] = src[(size_t)(cx + 8) * 64];
                float2 w;
                w.x = cRe * rRe - cIm * rIm;
                w.y = cRe * rIm + cIm * rRe;
                dst[(size_t)cx * 64] = w;
                float tRe = fmaf(lRe, rRe, fmaf(-lIm, rIm, v.x));
                float tIm = fmaf(lRe, rIm, fmaf(lIm, rRe, v.y));
                rRe = tRe; rIm = tIm;
            }
        }
    }
}

// ---------------------------------------------------------------- phase C: Y-GEMM + epilogue + fused next-state GEMM
__global__ __launch_bounds__(256) void phaseC_mfma(
        const float* __restrict__ u, float* __restrict__ uNext,
        const _Float16* __restrict__ AF, const _Float16* __restrict__ EF,
        const float* __restrict__ stW, float* __restrict__ stRaw,
        const float* __restrict__ Dp, const float* __restrict__ Wout,
        const float* __restrict__ bout, int layer,
        const float* __restrict__ W2, const float* __restrict__ b2,
        float* __restrict__ out, int isLast) {
    const int wv = threadIdx.x >> 6;
    const int lane = threadIdx.x & 63;
    const int quad = lane >> 4;
    const int li = lane & 15;
    const int gw = blockIdx.x * 4 + wv;          // 0..5119
    const int col = gw * 16 + li;
    const int b = col / CPAD;
    const int c = col - b * CPAD;
    const int cc = (c < CHK) ? c : (CHK - 1);
    const float* uB = u + (size_t)(b * HH) * LL + cc * TT;
    const float* wB = stW + ((size_t)b * CHK + cc) * 128;

    f32x4 acc[4][2];   // [lt][ch]
#pragma unroll
    for (int lt = 0; lt < 4; lt++)
#pragma unroll
        for (int ch = 0; ch < 2; ch++) acc[lt][ch] = (f32x4){0.f, 0.f, 0.f, 0.f};

#pragma unroll
    for (int kt = 0; kt < 4; kt++) {
#pragma unroll
        for (int ch = 0; ch < 2; ch++) {
            const _Float16* afb = AF + (size_t)(layer * 2 + ch) * 16384 + kt * 2048 + lane * 8;
            const float* src = (kt < 2)
                ? (uB + ch * LL + kt * 32 + quad * 8)
                : (wB + ch * 64 + (kt - 2) * 32 + quad * 8);
            f32x4 f0 = *(const f32x4*)src;
            f32x4 f1 = *(const f32x4*)(src + 4);
            half8 Bh, Bl; splitB(f0, f1, Bh, Bl);
#pragma unroll
            for (int lt = 0; lt < 4; lt++) {
                half8 Ah = *(const half8*)(afb + lt * 512);
                half8 Al = *(const half8*)(afb + 8192 + lt * 512);
                acc[lt][ch] = __builtin_amdgcn_mfma_f32_16x16x32_f16(Ah, Bh, acc[lt][ch], 0, 0, 0);
                acc[lt][ch] = __builtin_amdgcn_mfma_f32_16x16x32_f16(Ah, Bl, acc[lt][ch], 0, 0, 0);
                acc[lt][ch] = __builtin_amdgcn_mfma_f32_16x16x32_f16(Al, Bh, acc[lt][ch], 0, 0, 0);
            }
        }
    }

    // ---- fused epilogue
    float D0 = Dp[layer * HH + 0], D1 = Dp[layer * HH + 1];
    const float* Wo = Wout + layer * 8;
    const float* bo = bout + layer * 4;
    bool cOK = (c < CHK);
    f32x4 r0f[4], r1f[4];
#pragma unroll
    for (int lt = 0; lt < 4; lt++) {
        int l = lt * 16 + quad * 4;
        f32x4 u0 = *(const f32x4*)(uB + l);
        f32x4 u1 = *(const f32x4*)(uB + LL + l);
        f32x4 r0, r1;
#pragma unroll
        for (int r = 0; r < 4; r++) {
            float a0 = fmaf(D0, u0[r], acc[lt][0][r]);
            float a1 = fmaf(D1, u1[r], acc[lt][1][r]);
            a0 = 0.5f * a0 * (1.0f + erff(a0 * 0.70710678118654752f));
            a1 = 0.5f * a1 * (1.0f + erff(a1 * 0.70710678118654752f));
            float z0 = fmaf(Wo[0], a0, fmaf(Wo[1], a1, bo[0]));
            float z1 = fmaf(Wo[2], a0, fmaf(Wo[3], a1, bo[1]));
            float z2 = fmaf(Wo[4], a0, fmaf(Wo[5], a1, bo[2]));
            float z3 = fmaf(Wo[6], a0, fmaf(Wo[7], a1, bo[3]));
            float g2 = 1.0f / (1.0f + expf(-z2));
            float g3 = 1.0f / (1.0f + expf(-z3));
            r0[r] = z0 * g2;
            r1[r] = z1 * g3;
        }
        r0f[lt] = r0; r1f[lt] = r1;
        bool ok = cOK && (c < CHK - 1 || lt == 0);
        if (!isLast) {
            if (ok) {
                float* p0 = uNext + (size_t)(b * HH) * LL + cc * TT + l;
                *(f32x4*)p0 = r0;
                *(f32x4*)(p0 + LL) = r1;
            }
        } else {
            if (ok) {
                float w20 = W2[0], w21 = W2[1], w22 = W2[2], w23 = W2[3];
                float b20 = b2[0], b21 = b2[1];
                float* op = out + ((size_t)b * LL + (size_t)cc * TT + l) * 2;
                f32x4 lo4, hi4;
                lo4[0] = fmaf(r0[0], w20, fmaf(r1[0], w21, b20));
                lo4[1] = fmaf(r0[0], w22, fmaf(r1[0], w23, b21));
                lo4[2] = fmaf(r0[1], w20, fmaf(r1[1], w21, b20));
                lo4[3] = fmaf(r0[1], w22, fmaf(r1[1], w23, b21));
                hi4[0] = fmaf(r0[2], w20, fmaf(r1[2], w21, b20));
                hi4[1] = fmaf(r0[2], w22, fmaf(r1[2], w23, b21));
                hi4[2] = fmaf(r0[3], w20, fmaf(r1[3], w21, b20));
                hi4[3] = fmaf(r0[3], w22, fmaf(r1[3], w23, b21));
                *(f32x4*)op = lo4;
                *(f32x4*)(op + 4) = hi4;
            }
        }
    }

    // ---- fused next-layer state GEMM (skip on last layer)
    if (!isLast) {
        f32x4 rmA[4], rmB[4];
#pragma unroll
        for (int lt = 0; lt < 4; lt++) {
            bool z = (c == CHK - 1) && (lt > 0);   // zero-pad partial chunk
            rmA[lt] = z ? (f32x4){0.f, 0.f, 0.f, 0.f} : r0f[lt];
            rmB[lt] = z ? (f32x4){0.f, 0.f, 0.f, 0.f} : r1f[lt];
        }
        f32x4 eacc[4][2];
#pragma unroll
        for (int lt = 0; lt < 4; lt++)
#pragma unroll
            for (int ch = 0; ch < 2; ch++) eacc[lt][ch] = (f32x4){0.f, 0.f, 0.f, 0.f};

#pragma unroll
        for (int ch = 0; ch < 2; ch++) {
#pragma unroll
            for (int kt = 0; kt < 2; kt++) {
                // reshuffle C-layout r values into B-fragment layout
                float bv[8];
#pragma unroll
                for (int j = 0; j < 8; j++) {
                    int srcLane = ((quad & 1) * 2 + (j >> 2)) * 16 + li;
                    float x0 = ch ? rmB[kt * 2 + 0][j & 3] : rmA[kt * 2 + 0][j & 3];
                    float x1 = ch ? rmB[kt * 2 + 1][j & 3] : rmA[kt * 2 + 1][j & 3];
                    float a = __shfl(x0, srcLane, 64);
                    float bb = __shfl(x1, srcLane, 64);
                    bv[j] = (quad & 2) ? bb : a;
                }
                half8 Bh, Bl;
#pragma unroll
                for (int e = 0; e < 8; e++) {
                    float v = bv[e];
                    float hi = __uint_as_float(__float_as_uint(v) & 0xFFFFE000u);
                    Bh[e] = (_Float16)hi;
                    Bl[e] = (_Float16)(v - hi);
                }
                const _Float16* efb = EF + (size_t)layer * 16384 + (layer >= 0 ? 0 : 0)
                                      + (size_t)(ch + 1 - 1) * 0;  // placeholder, real below
                efb = EF + ((size_t)(layer + 1) * 2 + ch) * 8192 + kt * 2048 + lane * 8;
#pragma unroll
                for (int lt = 0; lt < 4; lt++) {
                    half8 Eh = *(const half8*)(efb + lt * 512);
                    half8 El = *(const half8*)(efb + 4096 + lt * 512);
                    eacc[lt][ch] = __builtin_amdgcn_mfma_f32_16x16x32_f16(Eh, Bh, eacc[lt][ch], 0, 0, 0);
                    eacc[lt][ch] = __builtin_amdgcn_mfma_f32_16x16x32_f16(Eh, Bl, eacc[lt][ch], 0, 0, 0);
                    eacc[lt][ch] = __builtin_amdgcn_mfma_f32_16x16x32_f16(El, Bh, eacc[lt][ch], 0, 0, 0);
                }
            }
        }
        if (cOK) {
            float* sp = stRaw + ((size_t)b * CHK + c) * 128;
#pragma unroll
            for (int ch = 0; ch < 2; ch++)
#pragma unroll
                for (int lt = 0; lt < 4; lt++)
                    *(f32x4*)(sp + ch * 64 + lt * 16 + quad * 4) = eacc[lt][ch];
        }
    }
}

extern "C" void kernel_launch(void* const* d_in, const int* in_sizes, int n_in,
                              void* d_out, int out_size, void* d_ws, size_t ws_size,
                              hipStream_t stream) {
    const float* x         = (const float*)d_in[0];
    const float* W1        = (const float*)d_in[1];
    const float* b1        = (const float*)d_in[2];
    const float* W2        = (const float*)d_in[3];
    const float* b2        = (const float*)d_in[4];
    const float* log_dt    = (const float*)d_in[5];
    const float* log_A_real= (const float*)d_in[6];
    const float* A_imag    = (const float*)d_in[7];
    const float* Cin       = (const float*)d_in[8];
    const float* Dp        = (const float*)d_in[9];
    const float* Wout      = (const float*)d_in[10];
    const float* bout      = (const float*)d_in[11];
    float* out = (float*)d_out;
    float* ws = (float*)d_ws;

    float* U0   = ws + OFF_U0;
    float* U1   = ws + OFF_U1;
    float* S0   = ws + OFF_S0;     // raw states
    float* S1   = ws + OFF_S1;     // w
    float* lam  = ws + OFF_TAB;
    float* lamT = lam + 512;
    float* Cn   = lamT + 512;
    float* Kt   = Cn + 512;
    float* P    = Kt + 512;
    _Float16* AF = (_Float16*)(P + 32768);
    _Float16* EF = AF + 131072;

    setup_kernel<<<dim3(NL * HH), dim3(64), 0, stream>>>(log_dt, log_A_real, A_imag, Cin,
                                                         lam, lamT, Cn, Kt, P);
    setup2_kernel<<<dim3(NL * HH), dim3(64), 0, stream>>>(Kt, P, AF, EF);
    embed_kernel<<<dim3(BL / 256), dim3(256), 0, stream>>>(x, W1, b1, U0);
    phaseA_mfma<<<dim3(BB * CPAD / 64), dim3(256), 0, stream>>>(U0, EF, S0);

    float* cur = U0;
    float* nxt = U1;
    for (int i = 0; i < NL; i++) {
        phaseB_kernel<<<dim3(BB), dim3(64), 0, stream>>>(lamT, Cn, S0, S1, i);
        phaseC_mfma<<<dim3(BB * CPAD / 64), dim3(256), 0, stream>>>(cur, nxt, AF, EF, S1, S0,
                                                                    Dp, Wout, bout, i,
                                                                    W2, b2, out,
                                                                    (i == NL - 1) ? 1 : 0);
        float* tmp = cur; cur = nxt; nxt = tmp;
    }
}